// Round 8
// baseline (811.026 us; speedup 1.0000x reference)
//
#include <hip/hip_runtime.h>
#include <hip/hip_bf16.h>
#include <hip/hip_fp16.h>
#include <stdint.h>

typedef float f32x4 __attribute__((ext_vector_type(4)));
typedef short short8 __attribute__((ext_vector_type(8)));
typedef unsigned short ushort4_t __attribute__((ext_vector_type(4)));
typedef unsigned short u16;

#if defined(__has_builtin)
#if __has_builtin(__builtin_amdgcn_exp2f)
#define EXP2(x) __builtin_amdgcn_exp2f(x)
#else
#define EXP2(x) exp2f(x)
#endif
#else
#define EXP2(x) exp2f(x)
#endif

static __device__ __forceinline__ u16 f2bf(float f) {
    __hip_bfloat16 h = __float2bfloat16(f);
    return *reinterpret_cast<const u16*>(&h);
}
static __device__ __forceinline__ u16 f2h(float f) {
    __half h = __float2half(f);
    return *reinterpret_cast<const u16*>(&h);
}
static __device__ __forceinline__ float h2f(u16 b) {
    __half h = *reinterpret_cast<const __half*>(&b);
    return __half2float(h);
}

// async global->LDS, 16B per lane: LDS dest = wave-uniform base + lane*16,
// global src is per-lane (carries the swizzle).
static __device__ __forceinline__ void gload16(const void* g, void* l) {
    __builtin_amdgcn_global_load_lds((const __attribute__((address_space(1))) void*)g,
                                     (__attribute__((address_space(3))) void*)l, 16, 0, 0);
}

// ---------------- weights f32 -> bf16 cast, 3 arrays in one launch ----------------
__global__ void k_cast3(const float* __restrict__ a, const float* __restrict__ b,
                        const float* __restrict__ c, u16* __restrict__ oa,
                        u16* __restrict__ ob, u16* __restrict__ oc) {
    int i = blockIdx.x * blockDim.x + threadIdx.x;   // 3*65536 float4-groups
    int which = i >> 16, j = i & 65535;
    const float* in = (which == 0) ? a : (which == 1) ? b : c;
    u16* out = (which == 0) ? oa : (which == 1) ? ob : oc;
    float4 v = ((const float4*)in)[j];
    ushort4 o;
    o.x = f2bf(v.x); o.y = f2bf(v.y); o.z = f2bf(v.z); o.w = f2bf(v.w);
    ((ushort4*)out)[j] = o;
}

// ------------- transpose+cast: f32 [b][512][4096] -> bf16 [b][4096][512] -------------
__global__ __launch_bounds__(256) void k_transpose(const float* __restrict__ in, u16* __restrict__ out) {
    __shared__ float t[64][65];
    int b = blockIdx.z;
    int c0 = blockIdx.y * 64;
    int n0 = blockIdx.x * 64;
    const float* ip = in + ((size_t)b * 512 + c0) * 4096 + n0;
#pragma unroll
    for (int i = 0; i < 16; ++i) {
        int idx = threadIdx.x + i * 256;
        int cl = idx >> 6, nl = idx & 63;
        t[cl][nl] = ip[(size_t)cl * 4096 + nl];
    }
    __syncthreads();
    u16* op = out + ((size_t)b * 4096 + n0) * 512 + c0;
#pragma unroll
    for (int i = 0; i < 16; ++i) {
        int idx = threadIdx.x + i * 256;
        int nr = idx >> 6, cc = idx & 63;
        op[(size_t)nr * 512 + cc] = f2bf(t[cc][nr]);
    }
}

// ------------- content per-(b,c) mean / rstd (ddof=1, +eps) -------------
__global__ __launch_bounds__(256) void k_cstats(const float* __restrict__ content, float* __restrict__ cstat) {
    int c = blockIdx.x, b = blockIdx.y;
    const float4* r4 = (const float4*)(content + ((size_t)b * 512 + c) * 4096);
    float s = 0.f, ss = 0.f;
    for (int i = threadIdx.x; i < 1024; i += 256) {
        float4 v = r4[i];
        s += v.x + v.y + v.z + v.w;
        ss += v.x * v.x + v.y * v.y + v.z * v.z + v.w * v.w;
    }
#pragma unroll
    for (int k = 1; k < 64; k <<= 1) { s += __shfl_xor(s, k); ss += __shfl_xor(ss, k); }
    __shared__ float ls[4], lss[4];
    int w = threadIdx.x >> 6;
    if ((threadIdx.x & 63) == 0) { ls[w] = s; lss[w] = ss; }
    __syncthreads();
    if (threadIdx.x == 0) {
        s = ls[0] + ls[1] + ls[2] + ls[3];
        ss = lss[0] + lss[1] + lss[2] + lss[3];
        float mu = s / 4096.f;
        float var = (ss - 4096.f * mu * mu) / 4095.f;
        cstat[((size_t)b * 512 + c) * 2] = mu;
        cstat[((size_t)b * 512 + c) * 2 + 1] = rsqrtf(var + 1e-5f);
    }
}

// ------------- conv1x1, pixel-major output, XCD-pinned batches -------------
__global__ __launch_bounds__(256) void k_convP(const u16* __restrict__ XT, const u16* __restrict__ Wb,
                                               const float* __restrict__ bias, u16* __restrict__ out) {
    int bid = blockIdx.x;
    int b = (bid & 7) >> 1;
    int u = ((bid & 1) << 8) | (bid >> 3);
    int n0 = (u & 63) * 64, o0 = (u >> 6) * 64;
    int lane = threadIdx.x & 63, w = threadIdx.x >> 6;
    int l15 = lane & 15, l4 = lane >> 4;
    const u16* ap = XT + ((size_t)b * 4096 + n0 + w * 16 + l15) * 512 + l4 * 8;
    f32x4 acc[4] = {{0,0,0,0},{0,0,0,0},{0,0,0,0},{0,0,0,0}};
#pragma unroll
    for (int kk = 0; kk < 16; ++kk) {
        short8 a = *(const short8*)(ap + kk * 32);
#pragma unroll
        for (int bo = 0; bo < 4; ++bo) {
            const u16* bp = Wb + ((size_t)(o0 + bo * 16 + l15)) * 512 + kk * 32 + l4 * 8;
            short8 bb = *(const short8*)bp;
            acc[bo] = __builtin_amdgcn_mfma_f32_16x16x32_bf16(a, bb, acc[bo], 0, 0, 0);
        }
    }
#pragma unroll
    for (int bo = 0; bo < 4; ++bo) {
        float bv = bias[o0 + bo * 16 + l15];
#pragma unroll
        for (int r = 0; r < 4; ++r) {
            int n = n0 + w * 16 + l4 * 4 + r;
            out[((size_t)b * 4096 + n) * 512 + o0 + bo * 16 + l15] = f2bf(acc[bo][r] + bv);
        }
    }
}

// ------------- conv1x1, channel-major output + squares, XCD-pinned batches -------------
__global__ __launch_bounds__(256) void k_convH(const u16* __restrict__ ST, const u16* __restrict__ Wb,
                                               const float* __restrict__ bias, u16* __restrict__ out) {
    int bid = blockIdx.x;
    int b = (bid & 7) >> 1;
    int u = ((bid & 1) << 8) | (bid >> 3);
    int m0 = (u & 63) * 64, o0 = (u >> 6) * 64;
    int lane = threadIdx.x & 63, w = threadIdx.x >> 6;
    int l15 = lane & 15, l4 = lane >> 4;
    const u16* ap = Wb + ((size_t)(o0 + w * 16 + l15)) * 512 + l4 * 8;
    f32x4 acc[4] = {{0,0,0,0},{0,0,0,0},{0,0,0,0},{0,0,0,0}};
#pragma unroll
    for (int kk = 0; kk < 16; ++kk) {
        short8 a = *(const short8*)(ap + kk * 32);
#pragma unroll
        for (int mb = 0; mb < 4; ++mb) {
            const u16* bp = ST + ((size_t)b * 4096 + m0 + mb * 16 + l15) * 512 + kk * 32 + l4 * 8;
            short8 bb = *(const short8*)bp;
            acc[mb] = __builtin_amdgcn_mfma_f32_16x16x32_bf16(a, bb, acc[mb], 0, 0, 0);
        }
    }
#pragma unroll
    for (int r = 0; r < 4; ++r) {
        int o = o0 + w * 16 + l4 * 4 + r;
        float bv = bias[o];
#pragma unroll
        for (int mb = 0; mb < 4; ++mb) {
            float v = acc[mb][r] + bv;
            size_t base = ((size_t)b * 1024 + o) * 4096 + m0 + mb * 16 + l15;
            out[base] = f2bf(v);
            out[base + (size_t)512 * 4096] = f2bf(v * v);
        }
    }
}

// ============ kernel A: QK (swapped operands) + softmax stats + fp16 logits*log2e ============
// grid 512: b=(bid&7)>>1; half=bid&1 (per-XCD G slice 2 MB, L2-resident); qt=bid>>3.
// mfma(G,Q): D row = kv (lane's 4 consecutive), col = q (l15) -> per-lane scalar stats,
// packed 8B fp16 logit stores. Lg stores v*log2e (pre-scaled for attnB's exp2 path).
__global__ __launch_bounds__(512, 4) void k_attnA(
    const u16* __restrict__ Q, const u16* __restrict__ G,
    u16* __restrict__ Lg, float* __restrict__ stats) {

    __shared__ __align__(16) u16 gtile[2][32 * 512];   // 2 x 32KB
    __shared__ float smd[4][2][16], ssd_[4][2][16], smsp[4][2][16], sssp[4][2][16];

    int bid = blockIdx.x;
    int b = (bid & 7) >> 1;
    int half = bid & 1;
    int qt = bid >> 3;
    int n0 = qt * 64;
    int kv0 = half * 2048;
    int lane = threadIdx.x & 63, w = threadIdx.x >> 6;
    int l15 = lane & 15, l4 = lane >> 4;
    int R = w >> 1, MB = w & 1;
    const float L2E = 1.44269504f;

    const u16* qp = Q + ((size_t)b * 4096 + n0 + R * 16 + l15) * 512 + l4 * 8;
    short8 q[16];
#pragma unroll
    for (int kk = 0; kk < 16; ++kk) q[kk] = *(const short8*)(qp + kk * 32);

    const char* gbat = (const char*)(G + (size_t)b * 4096 * 512);
    size_t lgoff = ((size_t)b * 4096 + n0 + R * 16 + l15) * 4096 + kv0 + MB * 16 + l4 * 4;

#define STAGEA(buf, mc)                                                                \
    {                                                                                  \
        _Pragma("unroll")                                                              \
        for (int j = 0; j < 4; ++j) {                                                  \
            int row = j * 8 + w;                                                       \
            const char* src = gbat + ((size_t)(kv0 + (mc) * 32 + row)) * 1024          \
                              + ((lane * 16) ^ ((row & 7) << 4));                      \
            gload16(src, (char*)&gtile[buf][0] + row * 1024);                          \
        }                                                                              \
    }

    float md = -1e30f, sd = 0.f, ms = -1e30f, ss = 0.f;

    STAGEA(0, 0);
    __syncthreads();
    for (int mc = 0; mc < 64; ++mc) {
        int buf = mc & 1;
        if (mc < 63) STAGEA(buf ^ 1, mc + 1);
        f32x4 acc = {0, 0, 0, 0};
        const char* gt = (const char*)&gtile[buf][0];
        int row = MB * 16 + l15;
#pragma unroll
        for (int kk = 0; kk < 16; ++kk) {
            int y = (kk * 64 + l4 * 16) ^ ((row & 7) << 4);
            short8 gg = *(const short8*)(gt + row * 1024 + y);
            acc = __builtin_amdgcn_mfma_f32_16x16x32_bf16(gg, q[kk], acc, 0, 0, 0);
        }
        float v0 = acc[0], v1 = acc[1], v2 = acc[2], v3 = acc[3];
        float mx = fmaxf(fmaxf(v0, v1), fmaxf(v2, v3));
        float mn = fmaxf(md, mx);
        sd = sd * __expf(md - mn) +
             ((__expf(v0 - mn) + __expf(v1 - mn)) + (__expf(v2 - mn) + __expf(v3 - mn)));
        md = mn;
        float mns = fmaxf(ms, fmaxf(mx, 0.f));
        ss = ss * __expf(ms - mns) +
             ((__expf(fmaxf(v0, 0.f) - mns) + __expf(fmaxf(v1, 0.f) - mns)) +
              (__expf(fmaxf(v2, 0.f) - mns) + __expf(fmaxf(v3, 0.f) - mns)));
        ms = mns;
        ushort4_t pk = {f2h(v0 * L2E), f2h(v1 * L2E), f2h(v2 * L2E), f2h(v3 * L2E)};
        *(ushort4_t*)(Lg + lgoff + (size_t)mc * 32) = pk;
        __syncthreads();
    }

    // merge the 4 l4-groups (same q-row): xor 16, 32
#pragma unroll
    for (int k = 16; k < 64; k <<= 1) {
        float mo = __shfl_xor(md, k), so = __shfl_xor(sd, k);
        float mn = fmaxf(md, mo);
        sd = sd * __expf(md - mn) + so * __expf(mo - mn);
        md = mn;
        mo = __shfl_xor(ms, k); so = __shfl_xor(ss, k);
        mn = fmaxf(ms, mo);
        ss = ss * __expf(ms - mn) + so * __expf(mo - mn);
        ms = mn;
    }
    if (l4 == 0) {
        smd[R][MB][l15] = md; ssd_[R][MB][l15] = sd;
        smsp[R][MB][l15] = ms; sssp[R][MB][l15] = ss;
    }
    __syncthreads();
    if (MB == 0 && lane < 16) {
        float m0_ = smd[R][0][l15], s0_ = ssd_[R][0][l15];
        float m1_ = smd[R][1][l15], s1_ = ssd_[R][1][l15];
        float mn = fmaxf(m0_, m1_);
        float Sd = s0_ * __expf(m0_ - mn) + s1_ * __expf(m1_ - mn);
        float Md = mn;
        m0_ = smsp[R][0][l15]; s0_ = sssp[R][0][l15];
        m1_ = smsp[R][1][l15]; s1_ = sssp[R][1][l15];
        mn = fmaxf(m0_, m1_);
        float Ss = s0_ * __expf(m0_ - mn) + s1_ * __expf(m1_ - mn);
        float Ms = mn;
        int qg = n0 + R * 16 + l15;
        float4 st = {Md, Sd, Ms, Ss};
        *(float4*)(stats + (((size_t)b * 4096 + qg) * 2 + half) * 4) = st;
    }
#undef STAGEA
}

// ============ kernel B v4: e = exp2 mix + PV + epilogue ============
// grid 256, 1024 threads (16 waves), 1 block/CU. Q=128, CH=512 (cs half).
// decode: b=(bid&7)>>1; qt=((bid&1)<<4)|(bid>>4) in 0..31; cs=(bid>>3)&1 —
// cs-twins (same Lg rows) land on the SAME XCD (L2 dedup, the round-7 lesson).
// producer: thread owns (q-row=tid>>3 of 128, kv-octet=(tid&7)*8) -> bf16 e-tile (dbuf),
// Lg register-pipelined 2 tiles ahead; exp2-direct with folded constants (VALU diet).
// consumer: wave w: qh=w&1 (64-q half), chw=w>>1 owns 32 mean-ch + 32 sec-ch.
__global__ __launch_bounds__(1024, 1) void k_attnB(
    const u16* __restrict__ Lg, const u16* __restrict__ H,
    const float* __restrict__ stats, const float* __restrict__ wmix,
    const float* __restrict__ content, const float* __restrict__ cstat,
    float* __restrict__ out) {

    __shared__ __align__(16) u16 et[2][8192];   // 2 x 16KB bf16 e-tile [128q][64kv]
    __shared__ float zrow[128];

    int bid = blockIdx.x;
    int b = (bid & 7) >> 1;
    int qt = ((bid & 1) << 4) | (bid >> 4);
    int cs = (bid >> 3) & 1;
    int n0 = qt * 128;
    int tid = threadIdx.x;
    int lane = tid & 63, w = tid >> 6;   // w 0..15
    int l15 = lane & 15, l4 = lane >> 4;
    int qh = w & 1, chw = w >> 1;

    const float L2E = 1.44269504f;
    float wa = wmix[0], wbv = wmix[1];
    float wmx = fmaxf(wa, wbv);
    float e0 = __expf(wa - wmx), e1 = __expf(wbv - wmx);
    float w0l = e0 / (e0 + e1) * L2E, w1l = e1 / (e0 + e1) * L2E;

    // producer identity + merged+folded stats: ed = 2^(t - md2), t = v*log2e (in Lg)
    int prow = tid >> 3;            // 0..127
    int kvb = (tid & 7) * 8;        // kv element offset
    float md2, ms2;
    {
        const float* sp = stats + (((size_t)b * 4096 + n0 + prow) * 2) * 4;
        float4 s0 = *(const float4*)sp;
        float4 s1 = *(const float4*)(sp + 4);
        float mn = fmaxf(s0.x, s1.x);
        float S = s0.y * __expf(s0.x - mn) + s1.y * __expf(s1.x - mn);
        md2 = mn * L2E + __log2f(S);
        mn = fmaxf(s0.z, s1.z);
        S = s0.w * __expf(s0.z - mn) + s1.w * __expf(s1.z - mn);
        ms2 = mn * L2E + __log2f(S);
    }
    const u16* lgrow = Lg + ((size_t)b * 4096 + n0 + prow) * 4096 + kvb;
    unsigned ewbyte = (unsigned)(prow * 128) +
                      (((unsigned)(tid & 7) * 16) ^ ((unsigned)(prow & 7) << 4));
    float z = 0.f;

#define PRODUCE(ebase, LV)                                                             \
    {                                                                                  \
        short8 L8 = (LV);                                                              \
        short8 ebf;                                                                    \
        float za = 0.f, zb = 0.f;                                                      \
        _Pragma("unroll")                                                              \
        for (int j = 0; j < 8; ++j) {                                                  \
            float t = h2f((u16)L8[j]);                                                 \
            float ed = EXP2(t - md2);                                                  \
            float es = EXP2(fmaxf(t, 0.f) - ms2);                                      \
            float e = EXP2(fmaf(w0l, ed, w1l * es));                                   \
            if (j & 1) zb += e; else za += e;                                          \
            ebf[j] = (short)f2bf(e);                                                   \
        }                                                                              \
        z += za + zb;                                                                  \
        *(short8*)((char*)(ebase) + ewbyte) = ebf;                                     \
    }

    f32x4 pv[16];
#pragma unroll
    for (int i = 0; i < 16; ++i) pv[i] = (f32x4){0, 0, 0, 0};

    short8 Lcur = *(const short8*)(lgrow);            // tile 0
    PRODUCE(&et[0][0], Lcur);
    short8 Lnext = *(const short8*)(lgrow + 64);      // tile 1
    __syncthreads();

    for (int mc = 0; mc < 64; ++mc) {
        int buf = mc & 1;
        if (mc < 63) {
            short8 Lp = Lnext;
            if (mc < 62) Lnext = *(const short8*)(lgrow + (size_t)(mc + 2) * 64);
            PRODUCE(&et[buf ^ 1][0], Lp);
        }
        const char* eb = (const char*)&et[buf][0];
        const u16* hb = H + (size_t)b * 1024 * 4096 + (size_t)mc * 64 + l4 * 8;
#pragma unroll
        for (int ks = 0; ks < 2; ++ks) {
            short8 af[4];
#pragma unroll
            for (int qf = 0; qf < 4; ++qf) {
                int qq = qh * 64 + qf * 16 + l15;
                int y = (ks * 64 + l4 * 16) ^ ((qq & 7) << 4);
                af[qf] = *(const short8*)(eb + qq * 128 + y);
            }
            __builtin_amdgcn_s_setprio(1);
#pragma unroll
            for (int cf = 0; cf < 4; ++cf) {
                int c = (cf < 2) ? (cs * 256 + chw * 32 + cf * 16 + l15)
                                 : (512 + cs * 256 + chw * 32 + (cf - 2) * 16 + l15);
                short8 hh = *(const short8*)(hb + (size_t)c * 4096 + ks * 32);
#pragma unroll
                for (int qf = 0; qf < 4; ++qf)
                    pv[qf * 4 + cf] = __builtin_amdgcn_mfma_f32_16x16x32_bf16(af[qf], hh, pv[qf * 4 + cf], 0, 0, 0);
            }
            __builtin_amdgcn_s_setprio(0);
        }
        __syncthreads();
    }

    // Z: reduce the 8 kv-octet threads of each q-row (contiguous lanes)
    z += __shfl_xor(z, 1);
    z += __shfl_xor(z, 2);
    z += __shfl_xor(z, 4);
    if ((tid & 7) == 0) zrow[prow] = z;
    __syncthreads();

    // epilogue: mean/std + fused mean_variance_norm(content), float4 I/O
#pragma unroll
    for (int qf = 0; qf < 4; ++qf) {
        float iz[4];
#pragma unroll
        for (int r = 0; r < 4; ++r)
            iz[r] = 1.f / zrow[qh * 64 + qf * 16 + l4 * 4 + r];
#pragma unroll
        for (int cf = 0; cf < 2; ++cf) {
            int c = cs * 256 + chw * 32 + cf * 16 + l15;
            float mu = cstat[((size_t)b * 512 + c) * 2];
            float rstd = cstat[((size_t)b * 512 + c) * 2 + 1];
            const float* cp = content + ((size_t)b * 512 + c) * 4096 + n0 + qh * 64 + qf * 16 + l4 * 4;
            float* op = out + ((size_t)b * 512 + c) * 4096 + n0 + qh * 64 + qf * 16 + l4 * 4;
            float4 cv = *(const float4*)cp;
            float4 ov;
#pragma unroll
            for (int r = 0; r < 4; ++r) {
                float mean = pv[qf * 4 + cf][r] * iz[r];
                float sec = pv[qf * 4 + cf + 2][r] * iz[r];
                float stdv = sqrtf(fmaxf(sec - mean * mean, 0.f));
                (&ov.x)[r] = stdv * ((&cv.x)[r] - mu) * rstd + mean;
            }
            *(float4*)op = ov;
        }
    }
#undef PRODUCE
}

extern "C" void kernel_launch(void* const* d_in, const int* in_sizes, int n_in,
                              void* d_out, int out_size, void* d_ws, size_t ws_size,
                              hipStream_t stream) {
    (void)in_sizes; (void)n_in; (void)out_size; (void)ws_size;
    const float* content = (const float*)d_in[0];
    const float* style   = (const float*)d_in[1];
    const float* ckey    = (const float*)d_in[2];
    const float* skey    = (const float*)d_in[3];
    const float* f_w = (const float*)d_in[4];
    const float* f_b = (const float*)d_in[5];
    const float* g_w = (const float*)d_in[6];
    const float* g_b = (const float*)d_in[7];
    const float* h_w = (const float*)d_in[8];
    const float* h_b = (const float*)d_in[9];
    const float* wmix = (const float*)d_in[10];
    float* out = (float*)d_out;

    const size_t MiB = 1048576;
    char* ws = (char*)d_ws;
    // Prep layout. Hb aliases ckT+skT (dead by convH time; same-stream serialization).
    u16* ckT = (u16*)(ws + 0);
    u16* skT = (u16*)(ws + 16 * MiB);
    u16* stT = (u16*)(ws + 32 * MiB);
    u16* fwB = (u16*)(ws + 48 * MiB);
    u16* gwB = (u16*)(ws + 48 * MiB + 524288);
    u16* hwB = (u16*)(ws + 49 * MiB);
    float* cst = (float*)(ws + 49 * MiB + 524288);   // 16 KB
    u16* Qb  = (u16*)(ws + 50 * MiB);
    u16* Gb  = (u16*)(ws + 66 * MiB);
    u16* Hb  = (u16*)(ws + 0);
    // fp16 logits*log2e [4][4096][4096] (128 MiB) + stats (512 KB)
    u16* Lg  = (u16*)(ws + 82 * MiB);
    float* stats = (float*)(ws + 210 * MiB);

    k_cast3<<<768, 256, 0, stream>>>(f_w, g_w, h_w, fwB, gwB, hwB);
    k_transpose<<<dim3(64, 8, 4), 256, 0, stream>>>(ckey, ckT);
    k_transpose<<<dim3(64, 8, 4), 256, 0, stream>>>(skey, skT);
    k_transpose<<<dim3(64, 8, 4), 256, 0, stream>>>(style, stT);
    k_cstats<<<dim3(512, 4), 256, 0, stream>>>(content, cst);
    k_convP<<<dim3(2048), 256, 0, stream>>>(ckT, fwB, f_b, Qb);
    k_convP<<<dim3(2048), 256, 0, stream>>>(skT, gwB, g_b, Gb);
    k_convH<<<dim3(2048), 256, 0, stream>>>(stT, hwB, h_b, Hb);
    k_attnA<<<dim3(512), 512, 0, stream>>>(Qb, Gb, Lg, stats);
    k_attnB<<<dim3(256), 1024, 0, stream>>>(Lg, Hb, stats, wmix, content, cst, out);
}

// Round 9
// 673.530 us; speedup vs baseline: 1.2041x; 1.2041x over previous
//
#include <hip/hip_runtime.h>
#include <hip/hip_bf16.h>
#include <hip/hip_fp16.h>
#include <stdint.h>

typedef float f32x4 __attribute__((ext_vector_type(4)));
typedef short short8 __attribute__((ext_vector_type(8)));
typedef unsigned short ushort4_t __attribute__((ext_vector_type(4)));
typedef unsigned short u16;

#if defined(__has_builtin)
#if __has_builtin(__builtin_amdgcn_exp2f)
#define EXP2(x) __builtin_amdgcn_exp2f(x)
#else
#define EXP2(x) exp2f(x)
#endif
#else
#define EXP2(x) exp2f(x)
#endif

static __device__ __forceinline__ u16 f2bf(float f) {
    __hip_bfloat16 h = __float2bfloat16(f);
    return *reinterpret_cast<const u16*>(&h);
}
static __device__ __forceinline__ u16 f2h(float f) {
    __half h = __float2half(f);
    return *reinterpret_cast<const u16*>(&h);
}
static __device__ __forceinline__ float h2f(u16 b) {
    __half h = *reinterpret_cast<const __half*>(&b);
    return __half2float(h);
}

// async global->LDS, 16B per lane: LDS dest = wave-uniform base + lane*16,
// global src is per-lane (carries the swizzle).
static __device__ __forceinline__ void gload16(const void* g, void* l) {
    __builtin_amdgcn_global_load_lds((const __attribute__((address_space(1))) void*)g,
                                     (__attribute__((address_space(3))) void*)l, 16, 0, 0);
}

// ---------------- weights f32 -> bf16 cast, 3 arrays in one launch ----------------
__global__ void k_cast3(const float* __restrict__ a, const float* __restrict__ b,
                        const float* __restrict__ c, u16* __restrict__ oa,
                        u16* __restrict__ ob, u16* __restrict__ oc) {
    int i = blockIdx.x * blockDim.x + threadIdx.x;   // 3*65536 float4-groups
    int which = i >> 16, j = i & 65535;
    const float* in = (which == 0) ? a : (which == 1) ? b : c;
    u16* out = (which == 0) ? oa : (which == 1) ? ob : oc;
    float4 v = ((const float4*)in)[j];
    ushort4 o;
    o.x = f2bf(v.x); o.y = f2bf(v.y); o.z = f2bf(v.z); o.w = f2bf(v.w);
    ((ushort4*)out)[j] = o;
}

// ------------- transpose+cast: f32 [b][512][4096] -> bf16 [b][4096][512] -------------
__global__ __launch_bounds__(256) void k_transpose(const float* __restrict__ in, u16* __restrict__ out) {
    __shared__ float t[64][65];
    int b = blockIdx.z;
    int c0 = blockIdx.y * 64;
    int n0 = blockIdx.x * 64;
    const float* ip = in + ((size_t)b * 512 + c0) * 4096 + n0;
#pragma unroll
    for (int i = 0; i < 16; ++i) {
        int idx = threadIdx.x + i * 256;
        int cl = idx >> 6, nl = idx & 63;
        t[cl][nl] = ip[(size_t)cl * 4096 + nl];
    }
    __syncthreads();
    u16* op = out + ((size_t)b * 4096 + n0) * 512 + c0;
#pragma unroll
    for (int i = 0; i < 16; ++i) {
        int idx = threadIdx.x + i * 256;
        int nr = idx >> 6, cc = idx & 63;
        op[(size_t)nr * 512 + cc] = f2bf(t[cc][nr]);
    }
}

// ------------- content per-(b,c) mean / rstd (ddof=1, +eps) -------------
__global__ __launch_bounds__(256) void k_cstats(const float* __restrict__ content, float* __restrict__ cstat) {
    int c = blockIdx.x, b = blockIdx.y;
    const float4* r4 = (const float4*)(content + ((size_t)b * 512 + c) * 4096);
    float s = 0.f, ss = 0.f;
    for (int i = threadIdx.x; i < 1024; i += 256) {
        float4 v = r4[i];
        s += v.x + v.y + v.z + v.w;
        ss += v.x * v.x + v.y * v.y + v.z * v.z + v.w * v.w;
    }
#pragma unroll
    for (int k = 1; k < 64; k <<= 1) { s += __shfl_xor(s, k); ss += __shfl_xor(ss, k); }
    __shared__ float ls[4], lss[4];
    int w = threadIdx.x >> 6;
    if ((threadIdx.x & 63) == 0) { ls[w] = s; lss[w] = ss; }
    __syncthreads();
    if (threadIdx.x == 0) {
        s = ls[0] + ls[1] + ls[2] + ls[3];
        ss = lss[0] + lss[1] + lss[2] + lss[3];
        float mu = s / 4096.f;
        float var = (ss - 4096.f * mu * mu) / 4095.f;
        cstat[((size_t)b * 512 + c) * 2] = mu;
        cstat[((size_t)b * 512 + c) * 2 + 1] = rsqrtf(var + 1e-5f);
    }
}

// ------------- conv1x1, pixel-major output, XCD-pinned batches -------------
__global__ __launch_bounds__(256) void k_convP(const u16* __restrict__ XT, const u16* __restrict__ Wb,
                                               const float* __restrict__ bias, u16* __restrict__ out) {
    int bid = blockIdx.x;
    int b = (bid & 7) >> 1;
    int u = ((bid & 1) << 8) | (bid >> 3);
    int n0 = (u & 63) * 64, o0 = (u >> 6) * 64;
    int lane = threadIdx.x & 63, w = threadIdx.x >> 6;
    int l15 = lane & 15, l4 = lane >> 4;
    const u16* ap = XT + ((size_t)b * 4096 + n0 + w * 16 + l15) * 512 + l4 * 8;
    f32x4 acc[4] = {{0,0,0,0},{0,0,0,0},{0,0,0,0},{0,0,0,0}};
#pragma unroll
    for (int kk = 0; kk < 16; ++kk) {
        short8 a = *(const short8*)(ap + kk * 32);
#pragma unroll
        for (int bo = 0; bo < 4; ++bo) {
            const u16* bp = Wb + ((size_t)(o0 + bo * 16 + l15)) * 512 + kk * 32 + l4 * 8;
            short8 bb = *(const short8*)bp;
            acc[bo] = __builtin_amdgcn_mfma_f32_16x16x32_bf16(a, bb, acc[bo], 0, 0, 0);
        }
    }
#pragma unroll
    for (int bo = 0; bo < 4; ++bo) {
        float bv = bias[o0 + bo * 16 + l15];
#pragma unroll
        for (int r = 0; r < 4; ++r) {
            int n = n0 + w * 16 + l4 * 4 + r;
            out[((size_t)b * 4096 + n) * 512 + o0 + bo * 16 + l15] = f2bf(acc[bo][r] + bv);
        }
    }
}

// ------------- conv1x1, channel-major output + squares, XCD-pinned batches -------------
__global__ __launch_bounds__(256) void k_convH(const u16* __restrict__ ST, const u16* __restrict__ Wb,
                                               const float* __restrict__ bias, u16* __restrict__ out) {
    int bid = blockIdx.x;
    int b = (bid & 7) >> 1;
    int u = ((bid & 1) << 8) | (bid >> 3);
    int m0 = (u & 63) * 64, o0 = (u >> 6) * 64;
    int lane = threadIdx.x & 63, w = threadIdx.x >> 6;
    int l15 = lane & 15, l4 = lane >> 4;
    const u16* ap = Wb + ((size_t)(o0 + w * 16 + l15)) * 512 + l4 * 8;
    f32x4 acc[4] = {{0,0,0,0},{0,0,0,0},{0,0,0,0},{0,0,0,0}};
#pragma unroll
    for (int kk = 0; kk < 16; ++kk) {
        short8 a = *(const short8*)(ap + kk * 32);
#pragma unroll
        for (int mb = 0; mb < 4; ++mb) {
            const u16* bp = ST + ((size_t)b * 4096 + m0 + mb * 16 + l15) * 512 + kk * 32 + l4 * 8;
            short8 bb = *(const short8*)bp;
            acc[mb] = __builtin_amdgcn_mfma_f32_16x16x32_bf16(a, bb, acc[mb], 0, 0, 0);
        }
    }
#pragma unroll
    for (int r = 0; r < 4; ++r) {
        int o = o0 + w * 16 + l4 * 4 + r;
        float bv = bias[o];
#pragma unroll
        for (int mb = 0; mb < 4; ++mb) {
            float v = acc[mb][r] + bv;
            size_t base = ((size_t)b * 1024 + o) * 4096 + m0 + mb * 16 + l15;
            out[base] = f2bf(v);
            out[base + (size_t)512 * 4096] = f2bf(v * v);
        }
    }
}

// ============ kernel A: QK (swapped operands) + softmax stats + fp16 logits*log2e ============
__global__ __launch_bounds__(512, 4) void k_attnA(
    const u16* __restrict__ Q, const u16* __restrict__ G,
    u16* __restrict__ Lg, float* __restrict__ stats) {

    __shared__ __align__(16) u16 gtile[2][32 * 512];   // 2 x 32KB
    __shared__ float smd[4][2][16], ssd_[4][2][16], smsp[4][2][16], sssp[4][2][16];

    int bid = blockIdx.x;
    int b = (bid & 7) >> 1;
    int half = bid & 1;
    int qt = bid >> 3;
    int n0 = qt * 64;
    int kv0 = half * 2048;
    int lane = threadIdx.x & 63, w = threadIdx.x >> 6;
    int l15 = lane & 15, l4 = lane >> 4;
    int R = w >> 1, MB = w & 1;
    const float L2E = 1.44269504f;

    const u16* qp = Q + ((size_t)b * 4096 + n0 + R * 16 + l15) * 512 + l4 * 8;
    short8 q[16];
#pragma unroll
    for (int kk = 0; kk < 16; ++kk) q[kk] = *(const short8*)(qp + kk * 32);

    const char* gbat = (const char*)(G + (size_t)b * 4096 * 512);
    size_t lgoff = ((size_t)b * 4096 + n0 + R * 16 + l15) * 4096 + kv0 + MB * 16 + l4 * 4;

#define STAGEA(buf, mc)                                                                \
    {                                                                                  \
        _Pragma("unroll")                                                              \
        for (int j = 0; j < 4; ++j) {                                                  \
            int row = j * 8 + w;                                                       \
            const char* src = gbat + ((size_t)(kv0 + (mc) * 32 + row)) * 1024          \
                              + ((lane * 16) ^ ((row & 7) << 4));                      \
            gload16(src, (char*)&gtile[buf][0] + row * 1024);                          \
        }                                                                              \
    }

    float md = -1e30f, sd = 0.f, ms = -1e30f, ss = 0.f;

    STAGEA(0, 0);
    __syncthreads();
    for (int mc = 0; mc < 64; ++mc) {
        int buf = mc & 1;
        if (mc < 63) STAGEA(buf ^ 1, mc + 1);
        f32x4 acc = {0, 0, 0, 0};
        const char* gt = (const char*)&gtile[buf][0];
        int row = MB * 16 + l15;
#pragma unroll
        for (int kk = 0; kk < 16; ++kk) {
            int y = (kk * 64 + l4 * 16) ^ ((row & 7) << 4);
            short8 gg = *(const short8*)(gt + row * 1024 + y);
            acc = __builtin_amdgcn_mfma_f32_16x16x32_bf16(gg, q[kk], acc, 0, 0, 0);
        }
        float v0 = acc[0], v1 = acc[1], v2 = acc[2], v3 = acc[3];
        float mx = fmaxf(fmaxf(v0, v1), fmaxf(v2, v3));
        float mn = fmaxf(md, mx);
        sd = sd * __expf(md - mn) +
             ((__expf(v0 - mn) + __expf(v1 - mn)) + (__expf(v2 - mn) + __expf(v3 - mn)));
        md = mn;
        float mns = fmaxf(ms, fmaxf(mx, 0.f));
        ss = ss * __expf(ms - mns) +
             ((__expf(fmaxf(v0, 0.f) - mns) + __expf(fmaxf(v1, 0.f) - mns)) +
              (__expf(fmaxf(v2, 0.f) - mns) + __expf(fmaxf(v3, 0.f) - mns)));
        ms = mns;
        ushort4_t pk = {f2h(v0 * L2E), f2h(v1 * L2E), f2h(v2 * L2E), f2h(v3 * L2E)};
        *(ushort4_t*)(Lg + lgoff + (size_t)mc * 32) = pk;
        __syncthreads();
    }

    // merge the 4 l4-groups (same q-row): xor 16, 32
#pragma unroll
    for (int k = 16; k < 64; k <<= 1) {
        float mo = __shfl_xor(md, k), so = __shfl_xor(sd, k);
        float mn = fmaxf(md, mo);
        sd = sd * __expf(md - mn) + so * __expf(mo - mn);
        md = mn;
        mo = __shfl_xor(ms, k); so = __shfl_xor(ss, k);
        mn = fmaxf(ms, mo);
        ss = ss * __expf(ms - mn) + so * __expf(mo - mn);
        ms = mn;
    }
    if (l4 == 0) {
        smd[R][MB][l15] = md; ssd_[R][MB][l15] = sd;
        smsp[R][MB][l15] = ms; sssp[R][MB][l15] = ss;
    }
    __syncthreads();
    if (MB == 0 && lane < 16) {
        float m0_ = smd[R][0][l15], s0_ = ssd_[R][0][l15];
        float m1_ = smd[R][1][l15], s1_ = ssd_[R][1][l15];
        float mn = fmaxf(m0_, m1_);
        float Sd = s0_ * __expf(m0_ - mn) + s1_ * __expf(m1_ - mn);
        float Md = mn;
        m0_ = smsp[R][0][l15]; s0_ = sssp[R][0][l15];
        m1_ = smsp[R][1][l15]; s1_ = sssp[R][1][l15];
        mn = fmaxf(m0_, m1_);
        float Ss = s0_ * __expf(m0_ - mn) + s1_ * __expf(m1_ - mn);
        float Ms = mn;
        int qg = n0 + R * 16 + l15;
        float4 st = {Md, Sd, Ms, Ss};
        *(float4*)(stats + (((size_t)b * 4096 + qg) * 2 + half) * 4) = st;
    }
#undef STAGEA
}

// ============ kernel B v5: H-tile LDS staging + exp2 producer + PV + epilogue ============
// grid 256, 1024 threads (16 waves), 1 block/CU. Q=128, CH=512 (cs half).
// decode (round-8, kept): b=(bid&7)>>1 (XCD-pinned batch); qt=((bid&1)<<4)|(bid>>4);
// cs=(bid>>3)&1 — cs-twins (same Lg rows) on the SAME XCD (Lg L2 dedup).
// NEW: H tile [512ch x 64kv] = 64 KB staged per mc via global_load_lds (4/thread),
// double-buffered + XOR-swizzled (rule 21: linear LDS dest, pre-swizzled global src).
// e-tile single-buffered (16 KB). LDS = 128 + 16.5 KB. Mid-barrier lgkmcnt-only so
// staging vmcnt rides across; end __syncthreads drains it (one phase of cover).
// LDS ht row r -> channel: r<256 ? cs*256+r : 512+cs*256+(r-256).
__global__ __launch_bounds__(1024, 1) void k_attnB(
    const u16* __restrict__ Lg, const u16* __restrict__ H,
    const float* __restrict__ stats, const float* __restrict__ wmix,
    const float* __restrict__ content, const float* __restrict__ cstat,
    float* __restrict__ out) {

    __shared__ __align__(16) u16 ht[2][512 * 64];   // 2 x 64 KB H tile (swizzled)
    __shared__ __align__(16) u16 et[8192];          // 16 KB e-tile [128q][64kv] (swizzled)
    __shared__ float zrow[128];

    int bid = blockIdx.x;
    int b = (bid & 7) >> 1;
    int qt = ((bid & 1) << 4) | (bid >> 4);
    int cs = (bid >> 3) & 1;
    int n0 = qt * 128;
    int tid = threadIdx.x;
    int lane = tid & 63, w = tid >> 6;   // w 0..15
    int l15 = lane & 15, l4 = lane >> 4;
    int qh = w & 1, chw = w >> 1;

    const float L2E = 1.44269504f;
    float wa = wmix[0], wbv = wmix[1];
    float wmx = fmaxf(wa, wbv);
    float e0 = __expf(wa - wmx), e1 = __expf(wbv - wmx);
    float w0l = e0 / (e0 + e1) * L2E, w1l = e1 / (e0 + e1) * L2E;

    // producer identity + merged+folded stats: ed = 2^(t - md2), t = v*log2e (in Lg)
    int prow = tid >> 3;            // 0..127
    int kvb = (tid & 7) * 8;        // kv element offset
    float md2, ms2;
    {
        const float* sp = stats + (((size_t)b * 4096 + n0 + prow) * 2) * 4;
        float4 s0 = *(const float4*)sp;
        float4 s1 = *(const float4*)(sp + 4);
        float mn = fmaxf(s0.x, s1.x);
        float S = s0.y * __expf(s0.x - mn) + s1.y * __expf(s1.x - mn);
        md2 = mn * L2E + __log2f(S);
        mn = fmaxf(s0.z, s1.z);
        S = s0.w * __expf(s0.z - mn) + s1.w * __expf(s1.z - mn);
        ms2 = mn * L2E + __log2f(S);
    }
    const u16* lgrow = Lg + ((size_t)b * 4096 + n0 + prow) * 4096 + kvb;
    unsigned ewbyte = (unsigned)(prow * 128) +
                      (((unsigned)(tid & 7) * 16) ^ ((unsigned)(prow & 7) << 4));
    float z = 0.f;

    // H staging: wave w, call j covers rows w*32+j*8 .. +8 (1 KB linear LDS, 64 lanes x 16B).
    // Lane's row = base + (lane>>3); row&7 == lane>>3. Global src pre-swizzled.
    const char* hbat = (const char*)(H + (size_t)b * 1024 * 4096);
#define STAGEH(buf, mc)                                                                \
    {                                                                                  \
        _Pragma("unroll")                                                              \
        for (int j = 0; j < 4; ++j) {                                                  \
            int row = w * 32 + j * 8 + (lane >> 3);                                    \
            int c = (row < 256) ? (cs * 256 + row) : (512 + cs * 256 + (row - 256));   \
            const char* src = hbat + (size_t)c * 8192 + (size_t)(mc) * 128             \
                              + ((((lane & 7) * 16)) ^ ((row & 7) << 4));              \
            gload16(src, (char*)&ht[buf][0] + (w * 32 + j * 8) * 128);                 \
        }                                                                              \
    }

#define PRODUCE(LV)                                                                    \
    {                                                                                  \
        short8 L8 = (LV);                                                              \
        short8 ebf;                                                                    \
        float za = 0.f, zb = 0.f;                                                      \
        _Pragma("unroll")                                                              \
        for (int j = 0; j < 8; ++j) {                                                  \
            float t = h2f((u16)L8[j]);                                                 \
            float ed = EXP2(t - md2);                                                  \
            float es = EXP2(fmaxf(t, 0.f) - ms2);                                      \
            float e = EXP2(fmaf(w0l, ed, w1l * es));                                   \
            if (j & 1) zb += e; else za += e;                                          \
            ebf[j] = (short)f2bf(e);                                                   \
        }                                                                              \
        z += za + zb;                                                                  \
        *(short8*)((char*)&et[0] + ewbyte) = ebf;                                      \
    }

    f32x4 pv[16];
#pragma unroll
    for (int i = 0; i < 16; ++i) pv[i] = (f32x4){0, 0, 0, 0};

    STAGEH(0, 0);
    short8 Lcur = *(const short8*)(lgrow);            // tile 0
    short8 Lnext = *(const short8*)(lgrow + 64);      // tile 1
    __syncthreads();   // drain ht[0]

    for (int mc = 0; mc < 64; ++mc) {
        int buf = mc & 1;
        if (mc < 63) STAGEH(buf ^ 1, mc + 1);          // issue early: covered by A+B phases
        PRODUCE(Lcur);
        Lcur = Lnext;
        if (mc < 62) Lnext = *(const short8*)(lgrow + (size_t)(mc + 2) * 64);

        // mid barrier: LDS drain only — keep staging vmcnt in flight
        asm volatile("s_waitcnt lgkmcnt(0)" ::: "memory");
        __builtin_amdgcn_s_barrier();
        __builtin_amdgcn_sched_barrier(0);

        const char* hb = (const char*)&ht[buf][0];
#pragma unroll
        for (int ks = 0; ks < 2; ++ks) {
            short8 af[4];
#pragma unroll
            for (int qf = 0; qf < 4; ++qf) {
                int qq = qh * 64 + qf * 16 + l15;
                int y = (ks * 64 + l4 * 16) ^ ((qq & 7) << 4);
                af[qf] = *(const short8*)((const char*)&et[0] + qq * 128 + y);
            }
            __builtin_amdgcn_s_setprio(1);
#pragma unroll
            for (int cf = 0; cf < 4; ++cf) {
                int row = (cf < 2) ? (chw * 32 + cf * 16 + l15)
                                   : (256 + chw * 32 + (cf - 2) * 16 + l15);
                int y = (ks * 64 + l4 * 16) ^ ((row & 7) << 4);
                short8 hh = *(const short8*)(hb + row * 128 + y);
#pragma unroll
                for (int qf = 0; qf < 4; ++qf)
                    pv[qf * 4 + cf] = __builtin_amdgcn_mfma_f32_16x16x32_bf16(af[qf], hh, pv[qf * 4 + cf], 0, 0, 0);
            }
            __builtin_amdgcn_s_setprio(0);
        }
        __syncthreads();   // et reuse + ht buffer flip + staging drain
    }

    // Z: reduce the 8 kv-octet threads of each q-row (contiguous lanes)
    z += __shfl_xor(z, 1);
    z += __shfl_xor(z, 2);
    z += __shfl_xor(z, 4);
    if ((tid & 7) == 0) zrow[prow] = z;
    __syncthreads();

    // epilogue: mean/std + fused mean_variance_norm(content), float4 I/O
#pragma unroll
    for (int qf = 0; qf < 4; ++qf) {
        float iz[4];
#pragma unroll
        for (int r = 0; r < 4; ++r)
            iz[r] = 1.f / zrow[qh * 64 + qf * 16 + l4 * 4 + r];
#pragma unroll
        for (int cf = 0; cf < 2; ++cf) {
            int c = cs * 256 + chw * 32 + cf * 16 + l15;
            float mu = cstat[((size_t)b * 512 + c) * 2];
            float rstd = cstat[((size_t)b * 512 + c) * 2 + 1];
            const float* cp = content + ((size_t)b * 512 + c) * 4096 + n0 + qh * 64 + qf * 16 + l4 * 4;
            float* op = out + ((size_t)b * 512 + c) * 4096 + n0 + qh * 64 + qf * 16 + l4 * 4;
            float4 cv = *(const float4*)cp;
            float4 ov;
#pragma unroll
            for (int r = 0; r < 4; ++r) {
                float mean = pv[qf * 4 + cf][r] * iz[r];
                float sec = pv[qf * 4 + cf + 2][r] * iz[r];
                float stdv = sqrtf(fmaxf(sec - mean * mean, 0.f));
                (&ov.x)[r] = stdv * ((&cv.x)[r] - mu) * rstd + mean;
            }
            *(float4*)op = ov;
        }
    }
#undef PRODUCE
#undef STAGEH
}

extern "C" void kernel_launch(void* const* d_in, const int* in_sizes, int n_in,
                              void* d_out, int out_size, void* d_ws, size_t ws_size,
                              hipStream_t stream) {
    (void)in_sizes; (void)n_in; (void)out_size; (void)ws_size;
    const float* content = (const float*)d_in[0];
    const float* style   = (const float*)d_in[1];
    const float* ckey    = (const float*)d_in[2];
    const float* skey    = (const float*)d_in[3];
    const float* f_w = (const float*)d_in[4];
    const float* f_b = (const float*)d_in[5];
    const float* g_w = (const float*)d_in[6];
    const float* g_b = (const float*)d_in[7];
    const float* h_w = (const float*)d_in[8];
    const float* h_b = (const float*)d_in[9];
    const float* wmix = (const float*)d_in[10];
    float* out = (float*)d_out;

    const size_t MiB = 1048576;
    char* ws = (char*)d_ws;
    // Prep layout. Hb aliases ckT+skT (dead by convH time; same-stream serialization).
    u16* ckT = (u16*)(ws + 0);
    u16* skT = (u16*)(ws + 16 * MiB);
    u16* stT = (u16*)(ws + 32 * MiB);
    u16* fwB = (u16*)(ws + 48 * MiB);
    u16* gwB = (u16*)(ws + 48 * MiB + 524288);
    u16* hwB = (u16*)(ws + 49 * MiB);
    float* cst = (float*)(ws + 49 * MiB + 524288);   // 16 KB
    u16* Qb  = (u16*)(ws + 50 * MiB);
    u16* Gb  = (u16*)(ws + 66 * MiB);
    u16* Hb  = (u16*)(ws + 0);
    // fp16 logits*log2e [4][4096][4096] (128 MiB) + stats (512 KB)
    u16* Lg  = (u16*)(ws + 82 * MiB);
    float* stats = (float*)(ws + 210 * MiB);

    k_cast3<<<768, 256, 0, stream>>>(f_w, g_w, h_w, fwB, gwB, hwB);
    k_transpose<<<dim3(64, 8, 4), 256, 0, stream>>>(ckey, ckT);
    k_transpose<<<dim3(64, 8, 4), 256, 0, stream>>>(skey, skT);
    k_transpose<<<dim3(64, 8, 4), 256, 0, stream>>>(style, stT);
    k_cstats<<<dim3(512, 4), 256, 0, stream>>>(content, cst);
    k_convP<<<dim3(2048), 256, 0, stream>>>(ckT, fwB, f_b, Qb);
    k_convP<<<dim3(2048), 256, 0, stream>>>(skT, gwB, g_b, Gb);
    k_convH<<<dim3(2048), 256, 0, stream>>>(stT, hwB, h_b, Hb);
    k_attnA<<<dim3(512), 512, 0, stream>>>(Qb, Gb, Lg, stats);
    k_attnB<<<dim3(256), 1024, 0, stream>>>(Lg, Hb, stats, wmix, content, cst, out);
}